// Round 5
// baseline (39.364 us; speedup 1.0000x reference)
//
#include <hip/hip_runtime.h>
#include <stdint.h>

#define BATCH 32768
#define NM 64
#define MARG 2e-4f

struct Keys { uint32_t k[8]; };

// Threefry-2x32, 20 rounds — matches jax._src.prng.threefry2x32 exactly.
__host__ __device__ inline void threefry2x32(uint32_t k0, uint32_t k1,
                                             uint32_t x0, uint32_t x1,
                                             uint32_t* o0, uint32_t* o1) {
  uint32_t k2 = k0 ^ k1 ^ 0x1BD11BDAu;
  x0 += k0; x1 += k1;
#define TF_RND(r) { x0 += x1; x1 = (x1 << (r)) | (x1 >> (32 - (r))); x1 ^= x0; }
  TF_RND(13) TF_RND(15) TF_RND(26) TF_RND(6)
  x0 += k1; x1 += k2 + 1u;
  TF_RND(17) TF_RND(29) TF_RND(16) TF_RND(24)
  x0 += k2; x1 += k0 + 2u;
  TF_RND(13) TF_RND(15) TF_RND(26) TF_RND(6)
  x0 += k0; x1 += k1 + 3u;
  TF_RND(17) TF_RND(29) TF_RND(16) TF_RND(24)
  x0 += k1; x1 += k2 + 4u;
  TF_RND(13) TF_RND(15) TF_RND(26) TF_RND(6)
  x0 += k2; x1 += k0 + 5u;
#undef TF_RND
  *o0 = x0; *o1 = x1;
}

// EXACT gumbel (OCML logf) — matches jax._src.random bit-exactly.
// Verified 0 argmax flips vs reference. Used for candidates + slow path only.
__device__ inline float gumbel_g(uint32_t bits) {
  float f = __uint_as_float((bits >> 9) | 0x3F800000u) - 1.0f;
  float u = fmaxf(1e-10f, f + 1e-10f);
  return -logf(-logf(u));
}

// CHEAP gumbel via hw v_log_f32; |err| <= ~1e-5 absolute (series guards the
// near-1 inner-log blowup; outer hw-log abs err <= ~8e-6 for |log2 t|<=23).
__device__ inline float gumbel_cheap(uint32_t bits) {
  float f = __uint_as_float((bits >> 9) | 0x3F800000u) - 1.0f;
  float u = fmaxf(1e-10f, f + 1e-10f);
  float w = 1.0f - u;                       // exact (Sterbenz, u>=0.5 branch-relevant)
  float t_log = -__logf(u);
  float t_ser = w * fmaf(w, fmaf(w, fmaf(w, 0.25f, 0.33333334f), 0.5f), 1.0f);
  float t = (w <= 0.03125f) ? t_ser : t_log;  // -ln(u), rel err <= ~7e-7
  return -__logf(t);
}

__device__ inline float tanh_fast(float x) {
  float e = __expf(2.0f * x);
#if __has_builtin(__builtin_amdgcn_rcpf)
  float r = __builtin_amdgcn_rcpf(e + 1.0f);
#else
  float r = 1.0f / (e + 1.0f);
#endif
  return fmaf(-2.0f, r, 1.0f);
}

// Block = 256 threads, 16 batch rows, 2048 blocks.
// Phase 1: 4 threads per (b,d,j); 16 CHEAP draws each; top-3 cheap merge;
//          guaranteed-exact resolve of top-2 candidates (1 exact draw/lane);
//          slow path (full exact, r4 code) when cheap margin is violated.
// Gates:   emitted right after winners (stores drain under phase 2).
// Phase 2: sparse MLP, one row per 16-lane group.
__global__ __launch_bounds__(256) void k_fused(Keys keys,
    const float* __restrict__ X,   const float* __restrict__ W1,
    const float* __restrict__ b1v, const float* __restrict__ W2,
    const float* __restrict__ b2v, const float* __restrict__ routers,
    const float* __restrict__ coef, const float* __restrict__ cp,
    float* __restrict__ out0, float4* __restrict__ gates) {
  __shared__ float basev[2][NM];
  __shared__ float xlds[16 * 2];
  __shared__ float part[64];
  __shared__ uint8_t wlds[4][16];

  const int t = threadIdx.x;
  const int b0 = blockIdx.x * 16;

  if (t < 128) basev[t >> 6][t & 63] = routers[t] + cp[t & 63];
  if (t < 32)  xlds[t] = X[b0 * 2 + t];
  __syncthreads();

  const int g = t >> 2, sub = t & 3;        // g = bl*4 + d*2 + j
  const int dj = g & 3, bl = g >> 2;
  const uint32_t k0 = keys.k[dj * 2 + 0], k1 = keys.k[dj * 2 + 1];
  const uint32_t rowbase = (uint32_t)(b0 + bl) * NM;
  const uint32_t ibase = rowbase + (uint32_t)sub * 16;
  // hoist the 16 base values into registers (static indexing only)
  const float4* bq = (const float4*)&basev[dj >> 1][sub * 16];
  const float4 q0 = bq[0], q1 = bq[1], q2 = bq[2], q3 = bq[3];
  const float bvr[16] = {q0.x, q0.y, q0.z, q0.w, q1.x, q1.y, q1.z, q1.w,
                         q2.x, q2.y, q2.z, q2.w, q3.x, q3.y, q3.z, q3.w};

  // ---- cheap pass: top-3 (z1>=z2>=z3), first-index kept on ties ----
  float z1 = -1e30f, z2 = -1e30f, z3 = -1e30f;
  int i1 = 0, i2 = 0;
#pragma unroll
  for (int mm = 0; mm < 16; ++mm) {
    uint32_t o0, o1;
    threefry2x32(k0, k1, 0u, ibase + (uint32_t)mm, &o0, &o1);
    float zc = bvr[mm] + gumbel_cheap(o0 ^ o1);
    int m = sub * 16 + mm;
    if (zc > z1)      { z3 = z2; z2 = z1; i2 = i1; z1 = zc; i1 = m; }
    else if (zc > z2) { z3 = z2; z2 = zc; i2 = m; }
    else if (zc > z3) { z3 = zc; }
  }
  // ---- merge top-3 across the 4 sub-lanes (butterfly) ----
#pragma unroll
  for (int dlt = 1; dlt <= 2; dlt <<= 1) {
    float oz1 = __shfl_xor(z1, dlt); int oi1 = __shfl_xor(i1, dlt);
    float oz2 = __shfl_xor(z2, dlt); int oi2 = __shfl_xor(i2, dlt);
    float oz3 = __shfl_xor(z3, dlt);
    bool afirst = (z1 > oz1) || (z1 == oz1 && i1 < oi1);
    float w1z = afirst ? z1 : oz1;  int w1i = afirst ? i1 : oi1;
    float l1z = afirst ? oz1 : z1;  int l1i = afirst ? oi1 : i1;
    float wz2 = afirst ? z2 : oz2;  int wi2 = afirst ? i2 : oi2;
    float lz2 = afirst ? oz2 : z2;
    float wz3 = afirst ? z3 : oz3;
    bool lfirst = (l1z > wz2) || (l1z == wz2 && l1i < wi2);
    float n2z = lfirst ? l1z : wz2; int n2i = lfirst ? l1i : wi2;
    float n3z = lfirst ? fmaxf(wz2, lz2) : fmaxf(l1z, wz3);
    z1 = w1z; i1 = w1i; z2 = n2z; i2 = n2i; z3 = n3z;
  }

  // ---- guaranteed-exact resolve of the two candidates (uniform, no arrays) ----
  const int ci = (sub & 2) ? i2 : i1;
  {
    uint32_t o0, o1;
    threefry2x32(k0, k1, 0u, rowbase + (uint32_t)ci, &o0, &o1);
    float ze = basev[dj >> 1][ci] + gumbel_g(o0 ^ o1);
    const int bl4 = (t & 63) & ~3;
    float z1e = __shfl(ze, bl4);            // exact z of candidate i1
    float z2e = __shfl(ze, bl4 + 2);        // exact z of candidate i2
    bool c1w = (z1e > z2e) || (z1e == z2e && i1 < i2);
    int best_i = c1w ? i1 : i2;
    int sec_i  = c1w ? i2 : i1;

    // ---- slow path: cheap margin violated -> full exact top-2 (r4 code) ----
    bool bad = (z3 > z2 - MARG);
    if (__any(bad)) {
      float eb = -1e30f, es = -1e30f;
      int ebi = 0, esi = 0;
#pragma unroll
      for (int mm = 0; mm < 16; ++mm) {
        uint32_t p0, p1;
        threefry2x32(k0, k1, 0u, ibase + (uint32_t)mm, &p0, &p1);
        float z = bvr[mm] + gumbel_g(p0 ^ p1);
        int m = sub * 16 + mm;
        if (z > eb)      { es = eb; esi = ebi; eb = z; ebi = m; }
        else if (z > es) { es = z; esi = m; }
      }
#pragma unroll
      for (int dlt = 1; dlt <= 2; dlt <<= 1) {
        float ob = __shfl_xor(eb, dlt);  int obi = __shfl_xor(ebi, dlt);
        float os = __shfl_xor(es, dlt);  int osi = __shfl_xor(esi, dlt);
        bool selfWins = (eb > ob) || (eb == ob && ebi < obi);
        if (selfWins) {
          if (ob > es || (ob == es && obi < esi)) { es = ob; esi = obi; }
        } else {
          if (eb > os || (eb == os && ebi < osi)) { es = eb; esi = ebi; }
          else { es = os; esi = osi; }
          eb = ob; ebi = obi;
        }
      }
      if (bad) { best_i = ebi; sec_i = esi; }
    }

    // ---- j=1 excludes j=0's winner; partner group is g^1 (4 lanes away) ----
    const int w0p = __shfl_xor(best_i, 4);
    const int w = ((g & 1) == 0) ? best_i : ((best_i == w0p) ? sec_i : best_i);
    if (sub == 0) wlds[dj][bl] = (uint8_t)w;
  }
  __syncthreads();

  // ---- gates: depend only on winners; stores drain under phase 2 ----
  {
    const int gb = t >> 4, q = t & 15;
    const int m0 = q * 4;
#pragma unroll
    for (int it = 0; it < 4; ++it) {
      const int gw = wlds[it][gb];
      float4 v;
      v.x = (m0 + 0 == gw) ? 1.0f : 0.0f;
      v.y = (m0 + 1 == gw) ? 1.0f : 0.0f;
      v.z = (m0 + 2 == gw) ? 1.0f : 0.0f;
      v.w = (m0 + 3 == gw) ? 1.0f : 0.0f;
      gates[(it * BATCH + b0 + gb) * 16 + q] = v;
    }
  }

  // ---- phase 2: sparse MLP, one row per 16-lane group ----
  const int wv = t >> 6, lane = t & 63;
  const int grp = lane >> 4, sl = lane & 15;
#pragma unroll
  for (int i = 0; i < 4; ++i) {
    const int r = wv * 16 + i * 4 + grp;    // row = rbl*4 + rdj
    const int rbl = r >> 2, rdj = r & 3;
    const int rw = wlds[rdj][rbl];
    const float xa = xlds[rbl * 2 + 0], xb = xlds[rbl * 2 + 1];
    const float4* A0 = (const float4*)(W1 + rw * 256 + sl * 8);
    const float4* A1 = (const float4*)(W1 + rw * 256 + 128 + sl * 8);
    const float4* B1 = (const float4*)(b1v + rw * 128 + sl * 8);
    const float4* WW = (const float4*)(W2 + rw * 128 + sl * 8);
    const float4 a0a = A0[0], a0b = A0[1];
    const float4 a1a = A1[0], a1b = A1[1];
    const float4 b1a = B1[0], b1b = B1[1];
    float h0 = fmaf(xb, a1a.x, fmaf(xa, a0a.x, b1a.x));
    float h1 = fmaf(xb, a1a.y, fmaf(xa, a0a.y, b1a.y));
    float h2 = fmaf(xb, a1a.z, fmaf(xa, a0a.z, b1a.z));
    float h3 = fmaf(xb, a1a.w, fmaf(xa, a0a.w, b1a.w));
    float h4 = fmaf(xb, a1b.x, fmaf(xa, a0b.x, b1b.x));
    float h5 = fmaf(xb, a1b.y, fmaf(xa, a0b.y, b1b.y));
    float h6 = fmaf(xb, a1b.z, fmaf(xa, a0b.z, b1b.z));
    float h7 = fmaf(xb, a1b.w, fmaf(xa, a0b.w, b1b.w));
    const float4 w2a = WW[0], w2b = WW[1];
    float s = tanh_fast(h0) * w2a.x;
    s = fmaf(tanh_fast(h1), w2a.y, s);
    s = fmaf(tanh_fast(h2), w2a.z, s);
    s = fmaf(tanh_fast(h3), w2a.w, s);
    s = fmaf(tanh_fast(h4), w2b.x, s);
    s = fmaf(tanh_fast(h5), w2b.y, s);
    s = fmaf(tanh_fast(h6), w2b.z, s);
    s = fmaf(tanh_fast(h7), w2b.w, s);
#pragma unroll
    for (int sft = 1; sft < 16; sft <<= 1) s += __shfl_xor(s, sft);
    if (sl == 0) part[r] = coef[rdj * NM + rw] * (s + b2v[rw]);
  }
  __syncthreads();

  // ---- out0 combine: fl(term_j0 + term_j1), matching reference order ----
  if (t < 32) {
    const int obl = t >> 1, od = t & 1;
    out0[(b0 + obl) * 2 + od] =
        part[obl * 4 + od * 2 + 0] + part[obl * 4 + od * 2 + 1];
  }
}

extern "C" void kernel_launch(void* const* d_in, const int* in_sizes, int n_in,
                              void* d_out, int out_size, void* d_ws, size_t ws_size,
                              hipStream_t stream) {
  const float* X       = (const float*)d_in[0];
  const float* W1      = (const float*)d_in[1];
  const float* b1v     = (const float*)d_in[2];
  const float* W2      = (const float*)d_in[3];
  const float* b2v     = (const float*)d_in[4];
  const float* routers = (const float*)d_in[5];
  const float* coef    = (const float*)d_in[6];
  const float* cp      = (const float*)d_in[7];
  float* out0  = (float*)d_out;
  float* gates = out0 + BATCH * 2;

  Keys keys;
  for (uint32_t dj = 0; dj < 4; ++dj) {
    uint32_t o0, o1;
    threefry2x32(0u, 42u, 0u, dj, &o0, &o1);
    keys.k[dj * 2 + 0] = o0;
    keys.k[dj * 2 + 1] = o1;
  }

  k_fused<<<dim3(BATCH / 16), dim3(256), 0, stream>>>(
      keys, X, W1, b1v, W2, b2v, routers, coef, cp, out0, (float4*)gates);
}

// Round 6
// 37.165 us; speedup vs baseline: 1.0592x; 1.0592x over previous
//
#include <hip/hip_runtime.h>
#include <stdint.h>

#define BATCH 32768
#define NM 64
#define MARG 2e-4f

struct Keys { uint32_t k[8]; };

// Threefry-2x32, 20 rounds — matches jax._src.prng.threefry2x32 exactly.
__host__ __device__ inline void threefry2x32(uint32_t k0, uint32_t k1,
                                             uint32_t x0, uint32_t x1,
                                             uint32_t* o0, uint32_t* o1) {
  uint32_t k2 = k0 ^ k1 ^ 0x1BD11BDAu;
  x0 += k0; x1 += k1;
#define TF_RND(r) { x0 += x1; x1 = (x1 << (r)) | (x1 >> (32 - (r))); x1 ^= x0; }
  TF_RND(13) TF_RND(15) TF_RND(26) TF_RND(6)
  x0 += k1; x1 += k2 + 1u;
  TF_RND(17) TF_RND(29) TF_RND(16) TF_RND(24)
  x0 += k2; x1 += k0 + 2u;
  TF_RND(13) TF_RND(15) TF_RND(26) TF_RND(6)
  x0 += k0; x1 += k1 + 3u;
  TF_RND(17) TF_RND(29) TF_RND(16) TF_RND(24)
  x0 += k1; x1 += k2 + 4u;
  TF_RND(13) TF_RND(15) TF_RND(26) TF_RND(6)
  x0 += k2; x1 += k0 + 5u;
#undef TF_RND
  *o0 = x0; *o1 = x1;
}

// EXACT gumbel (OCML logf) — matches jax._src.random bit-exactly.
// Verified 0 argmax flips vs reference. Candidates + slow path only.
__device__ inline float gumbel_g(uint32_t bits) {
  float f = __uint_as_float((bits >> 9) | 0x3F800000u) - 1.0f;
  float u = fmaxf(1e-10f, f + 1e-10f);
  return -logf(-logf(u));
}

// Raw hardware v_log_f32 (log BASE 2, 1 TRANS instr). r5 lesson: __logf
// lowered to an expensive OCML routine — force the builtin.
__device__ inline float fast_log2(float x) {
#if __has_builtin(__builtin_amdgcn_logf)
  return __builtin_amdgcn_logf(x);
#else
  return __log2f(x);
#endif
}

// CHEAP gumbel: |err| <= ~1e-6 abs. Series guards w=1-u<=1/32 (keeps the hw
// path at |log2 u| >= 0.046 where 1-ulp-of-result error is tiny);
// outer: t in [0.03,23], err ~<= 1e-6. MARG gives 200x headroom.
__device__ inline float gumbel_cheap(uint32_t bits) {
  float f = __uint_as_float((bits >> 9) | 0x3F800000u) - 1.0f;
  float u = fmaxf(1e-10f, f + 1e-10f);
  float w = 1.0f - u;                       // exact where it matters (u>=0.5)
  float t_log = fast_log2(u) * -0.69314718f;
  float t_ser = w * fmaf(w, fmaf(w, fmaf(w, 0.25f, 0.33333334f), 0.5f), 1.0f);
  float t = (w <= 0.03125f) ? t_ser : t_log;   // t = -ln(u)
  return fast_log2(t) * -0.69314718f;          // g = -ln(t)
}

__device__ inline float tanh_fast(float x) {
  float e = __expf(2.0f * x);
#if __has_builtin(__builtin_amdgcn_rcpf)
  float r = __builtin_amdgcn_rcpf(e + 1.0f);
#else
  float r = 1.0f / (e + 1.0f);
#endif
  return fmaf(-2.0f, r, 1.0f);
}

// Block = 256 threads, 16 batch rows, 2048 blocks.
// Phase 1: 4 threads per (b,d,j); 16 CHEAP draws (hw v_log); top-3 merge;
//          guaranteed-exact resolve of top-2 candidates; exact slow path
//          when cheap margin is violated (~1% of waves).
// Gates:   emitted right after winners (stores drain under phase 2).
// Phase 2: sparse MLP, one row per 16-lane group.
__global__ __launch_bounds__(256) void k_fused(Keys keys,
    const float* __restrict__ X,   const float* __restrict__ W1,
    const float* __restrict__ b1v, const float* __restrict__ W2,
    const float* __restrict__ b2v, const float* __restrict__ routers,
    const float* __restrict__ coef, const float* __restrict__ cp,
    float* __restrict__ out0, float4* __restrict__ gates) {
  __shared__ float basev[2][NM];
  __shared__ float xlds[16 * 2];
  __shared__ float part[64];
  __shared__ uint8_t wlds[4][16];

  const int t = threadIdx.x;
  const int b0 = blockIdx.x * 16;

  if (t < 128) basev[t >> 6][t & 63] = routers[t] + cp[t & 63];
  if (t < 32)  xlds[t] = X[b0 * 2 + t];
  __syncthreads();

  const int g = t >> 2, sub = t & 3;        // g = bl*4 + d*2 + j
  const int dj = g & 3, bl = g >> 2;
  const uint32_t k0 = keys.k[dj * 2 + 0], k1 = keys.k[dj * 2 + 1];
  const uint32_t rowbase = (uint32_t)(b0 + bl) * NM;
  const uint32_t ibase = rowbase + (uint32_t)sub * 16;
  // hoist the 16 base values into registers (static indexing only)
  const float4* bq = (const float4*)&basev[dj >> 1][sub * 16];
  const float4 q0 = bq[0], q1 = bq[1], q2 = bq[2], q3 = bq[3];
  const float bvr[16] = {q0.x, q0.y, q0.z, q0.w, q1.x, q1.y, q1.z, q1.w,
                         q2.x, q2.y, q2.z, q2.w, q3.x, q3.y, q3.z, q3.w};

  // ---- cheap pass: top-3 (z1>=z2>=z3), first-index kept on ties ----
  float z1 = -1e30f, z2 = -1e30f, z3 = -1e30f;
  int i1 = 0, i2 = 0;
#pragma unroll
  for (int mm = 0; mm < 16; ++mm) {
    uint32_t o0, o1;
    threefry2x32(k0, k1, 0u, ibase + (uint32_t)mm, &o0, &o1);
    float zc = bvr[mm] + gumbel_cheap(o0 ^ o1);
    int m = sub * 16 + mm;
    if (zc > z1)      { z3 = z2; z2 = z1; i2 = i1; z1 = zc; i1 = m; }
    else if (zc > z2) { z3 = z2; z2 = zc; i2 = m; }
    else if (zc > z3) { z3 = zc; }
  }
  // ---- merge top-3 across the 4 sub-lanes (butterfly) ----
#pragma unroll
  for (int dlt = 1; dlt <= 2; dlt <<= 1) {
    float oz1 = __shfl_xor(z1, dlt); int oi1 = __shfl_xor(i1, dlt);
    float oz2 = __shfl_xor(z2, dlt); int oi2 = __shfl_xor(i2, dlt);
    float oz3 = __shfl_xor(z3, dlt);
    bool afirst = (z1 > oz1) || (z1 == oz1 && i1 < oi1);
    float w1z = afirst ? z1 : oz1;  int w1i = afirst ? i1 : oi1;
    float l1z = afirst ? oz1 : z1;  int l1i = afirst ? oi1 : i1;
    float wz2 = afirst ? z2 : oz2;  int wi2 = afirst ? i2 : oi2;
    float lz2 = afirst ? oz2 : z2;
    float wz3 = afirst ? z3 : oz3;
    bool lfirst = (l1z > wz2) || (l1z == wz2 && l1i < wi2);
    float n2z = lfirst ? l1z : wz2; int n2i = lfirst ? l1i : wi2;
    float n3z = lfirst ? fmaxf(wz2, lz2) : fmaxf(l1z, wz3);
    z1 = w1z; i1 = w1i; z2 = n2z; i2 = n2i; z3 = n3z;
  }

  // ---- guaranteed-exact resolve of the two candidates (uniform) ----
  const int ci = (sub & 2) ? i2 : i1;
  {
    uint32_t o0, o1;
    threefry2x32(k0, k1, 0u, rowbase + (uint32_t)ci, &o0, &o1);
    float ze = basev[dj >> 1][ci] + gumbel_g(o0 ^ o1);
    const int bl4 = (t & 63) & ~3;
    float z1e = __shfl(ze, bl4);            // exact z of candidate i1
    float z2e = __shfl(ze, bl4 + 2);        // exact z of candidate i2
    bool c1w = (z1e > z2e) || (z1e == z2e && i1 < i2);
    int best_i = c1w ? i1 : i2;
    int sec_i  = c1w ? i2 : i1;

    // ---- slow path: cheap margin violated -> full exact top-2 ----
    bool bad = (z3 > z2 - MARG);
    if (__any(bad)) {
      float eb = -1e30f, es = -1e30f;
      int ebi = 0, esi = 0;
#pragma unroll
      for (int mm = 0; mm < 16; ++mm) {
        uint32_t p0, p1;
        threefry2x32(k0, k1, 0u, ibase + (uint32_t)mm, &p0, &p1);
        float z = bvr[mm] + gumbel_g(p0 ^ p1);
        int m = sub * 16 + mm;
        if (z > eb)      { es = eb; esi = ebi; eb = z; ebi = m; }
        else if (z > es) { es = z; esi = m; }
      }
#pragma unroll
      for (int dlt = 1; dlt <= 2; dlt <<= 1) {
        float ob = __shfl_xor(eb, dlt);  int obi = __shfl_xor(ebi, dlt);
        float os = __shfl_xor(es, dlt);  int osi = __shfl_xor(esi, dlt);
        bool selfWins = (eb > ob) || (eb == ob && ebi < obi);
        if (selfWins) {
          if (ob > es || (ob == es && obi < esi)) { es = ob; esi = obi; }
        } else {
          if (eb > os || (eb == os && ebi < osi)) { es = eb; esi = ebi; }
          else { es = os; esi = osi; }
          eb = ob; ebi = obi;
        }
      }
      if (bad) { best_i = ebi; sec_i = esi; }
    }

    // ---- j=1 excludes j=0's winner; partner group is g^1 (4 lanes away) ----
    const int w0p = __shfl_xor(best_i, 4);
    const int w = ((g & 1) == 0) ? best_i : ((best_i == w0p) ? sec_i : best_i);
    if (sub == 0) wlds[dj][bl] = (uint8_t)w;
  }
  __syncthreads();

  // ---- gates: depend only on winners; stores drain under phase 2 ----
  {
    const int gb = t >> 4, q = t & 15;
    const int m0 = q * 4;
#pragma unroll
    for (int it = 0; it < 4; ++it) {
      const int gw = wlds[it][gb];
      float4 v;
      v.x = (m0 + 0 == gw) ? 1.0f : 0.0f;
      v.y = (m0 + 1 == gw) ? 1.0f : 0.0f;
      v.z = (m0 + 2 == gw) ? 1.0f : 0.0f;
      v.w = (m0 + 3 == gw) ? 1.0f : 0.0f;
      gates[(it * BATCH + b0 + gb) * 16 + q] = v;
    }
  }

  // ---- phase 2: sparse MLP, one row per 16-lane group ----
  const int wv = t >> 6, lane = t & 63;
  const int grp = lane >> 4, sl = lane & 15;
#pragma unroll
  for (int i = 0; i < 4; ++i) {
    const int r = wv * 16 + i * 4 + grp;    // row = rbl*4 + rdj
    const int rbl = r >> 2, rdj = r & 3;
    const int rw = wlds[rdj][rbl];
    const float xa = xlds[rbl * 2 + 0], xb = xlds[rbl * 2 + 1];
    const float4* A0 = (const float4*)(W1 + rw * 256 + sl * 8);
    const float4* A1 = (const float4*)(W1 + rw * 256 + 128 + sl * 8);
    const float4* B1 = (const float4*)(b1v + rw * 128 + sl * 8);
    const float4* WW = (const float4*)(W2 + rw * 128 + sl * 8);
    const float4 a0a = A0[0], a0b = A0[1];
    const float4 a1a = A1[0], a1b = A1[1];
    const float4 b1a = B1[0], b1b = B1[1];
    float h0 = fmaf(xb, a1a.x, fmaf(xa, a0a.x, b1a.x));
    float h1 = fmaf(xb, a1a.y, fmaf(xa, a0a.y, b1a.y));
    float h2 = fmaf(xb, a1a.z, fmaf(xa, a0a.z, b1a.z));
    float h3 = fmaf(xb, a1a.w, fmaf(xa, a0a.w, b1a.w));
    float h4 = fmaf(xb, a1b.x, fmaf(xa, a0b.x, b1b.x));
    float h5 = fmaf(xb, a1b.y, fmaf(xa, a0b.y, b1b.y));
    float h6 = fmaf(xb, a1b.z, fmaf(xa, a0b.z, b1b.z));
    float h7 = fmaf(xb, a1b.w, fmaf(xa, a0b.w, b1b.w));
    const float4 w2a = WW[0], w2b = WW[1];
    float s = tanh_fast(h0) * w2a.x;
    s = fmaf(tanh_fast(h1), w2a.y, s);
    s = fmaf(tanh_fast(h2), w2a.z, s);
    s = fmaf(tanh_fast(h3), w2a.w, s);
    s = fmaf(tanh_fast(h4), w2b.x, s);
    s = fmaf(tanh_fast(h5), w2b.y, s);
    s = fmaf(tanh_fast(h6), w2b.z, s);
    s = fmaf(tanh_fast(h7), w2b.w, s);
#pragma unroll
    for (int sft = 1; sft < 16; sft <<= 1) s += __shfl_xor(s, sft);
    if (sl == 0) part[r] = coef[rdj * NM + rw] * (s + b2v[rw]);
  }
  __syncthreads();

  // ---- out0 combine: fl(term_j0 + term_j1), matching reference order ----
  if (t < 32) {
    const int obl = t >> 1, od = t & 1;
    out0[(b0 + obl) * 2 + od] =
        part[obl * 4 + od * 2 + 0] + part[obl * 4 + od * 2 + 1];
  }
}

extern "C" void kernel_launch(void* const* d_in, const int* in_sizes, int n_in,
                              void* d_out, int out_size, void* d_ws, size_t ws_size,
                              hipStream_t stream) {
  const float* X       = (const float*)d_in[0];
  const float* W1      = (const float*)d_in[1];
  const float* b1v     = (const float*)d_in[2];
  const float* W2      = (const float*)d_in[3];
  const float* b2v     = (const float*)d_in[4];
  const float* routers = (const float*)d_in[5];
  const float* coef    = (const float*)d_in[6];
  const float* cp      = (const float*)d_in[7];
  float* out0  = (float*)d_out;
  float* gates = out0 + BATCH * 2;

  Keys keys;
  for (uint32_t dj = 0; dj < 4; ++dj) {
    uint32_t o0, o1;
    threefry2x32(0u, 42u, 0u, dj, &o0, &o1);
    keys.k[dj * 2 + 0] = o0;
    keys.k[dj * 2 + 1] = o1;
  }

  k_fused<<<dim3(BATCH / 16), dim3(256), 0, stream>>>(
      keys, X, W1, b1v, W2, b2v, routers, coef, cp, out0, (float4*)gates);
}

// Round 7
// 35.350 us; speedup vs baseline: 1.1136x; 1.0513x over previous
//
#include <hip/hip_runtime.h>
#include <stdint.h>

#define BATCH 32768
#define NM 64

struct Keys { uint32_t k[8]; };

// Threefry-2x32, 20 rounds — matches jax._src.prng.threefry2x32 exactly.
__host__ __device__ inline void threefry2x32(uint32_t k0, uint32_t k1,
                                             uint32_t x0, uint32_t x1,
                                             uint32_t* o0, uint32_t* o1) {
  uint32_t k2 = k0 ^ k1 ^ 0x1BD11BDAu;
  x0 += k0; x1 += k1;
#define TF_RND(r) { x0 += x1; x1 = (x1 << (r)) | (x1 >> (32 - (r))); x1 ^= x0; }
  TF_RND(13) TF_RND(15) TF_RND(26) TF_RND(6)
  x0 += k1; x1 += k2 + 1u;
  TF_RND(17) TF_RND(29) TF_RND(16) TF_RND(24)
  x0 += k2; x1 += k0 + 2u;
  TF_RND(13) TF_RND(15) TF_RND(26) TF_RND(6)
  x0 += k0; x1 += k1 + 3u;
  TF_RND(17) TF_RND(29) TF_RND(16) TF_RND(24)
  x0 += k1; x1 += k2 + 4u;
  TF_RND(13) TF_RND(15) TF_RND(26) TF_RND(6)
  x0 += k2; x1 += k0 + 5u;
#undef TF_RND
  *o0 = x0; *o1 = x1;
}

// EXACT gumbel (OCML logf) — matches jax._src.random bit-exactly.
// Verified 0 argmax flips vs reference. DO NOT TOUCH.
__device__ inline float gumbel_g(uint32_t bits) {
  float f = __uint_as_float((bits >> 9) | 0x3F800000u) - 1.0f;
  float u = fmaxf(1e-10f, f + 1e-10f);
  return -logf(-logf(u));
}

__device__ inline float tanh_fast(float x) {
  float e = __expf(2.0f * x);
#if __has_builtin(__builtin_amdgcn_rcpf)
  float r = __builtin_amdgcn_rcpf(e + 1.0f);
#else
  float r = 1.0f / (e + 1.0f);
#endif
  return fmaf(-2.0f, r, 1.0f);
}

// BARRIER-FREE, LDS-FREE fused kernel. Block = 256 = 4 independent waves;
// each wave owns 4 batch rows x 4 (d,j) = 16 rows end-to-end:
//   phase 1: 4 lanes per row, 16 exact draws each, top-2 shfl merge (r4 math)
//   gates:   one-hot float4 stores (issued early; drain under phase 2)
//   phase 2: sparse MLP, one row per 16-lane group; rw via shfl; SGPR-base+
//            voffset addressing; out0 pair-combine via shfl_xor(.,16).
// All communication is intra-wave shfl -> zero __syncthreads, zero LDS.
__global__ __launch_bounds__(256) void k_fused(Keys keys,
    const float* __restrict__ X,   const float* __restrict__ W1,
    const float* __restrict__ b1v, const float* __restrict__ W2,
    const float* __restrict__ b2v, const float* __restrict__ routers,
    const float* __restrict__ coef, const float* __restrict__ cp,
    float* __restrict__ out0, float4* __restrict__ gates) {
  const int t = threadIdx.x;
  const int wv = t >> 6, lane = t & 63;
  const int b0w = blockIdx.x * 16 + wv * 4;   // this wave's first batch row

  // ---- phase 1: exact top-2 gumbel argmax (bit-identical to r4) ----
  const int g = lane >> 2, sub = lane & 3;    // g = bl*4 + dj, bl local 0..3
  const int dj = g & 3, bl = g >> 2;
  const uint32_t k0 = keys.k[dj * 2 + 0], k1 = keys.k[dj * 2 + 1];
  const uint32_t ibase = (uint32_t)(b0w + bl) * NM + (uint32_t)sub * 16;

  // base logits straight from global (768 B total, L2-resident)
  const float4* rq = (const float4*)(routers + (dj >> 1) * NM + sub * 16);
  const float4* cq = (const float4*)(cp + sub * 16);
  const float4 r0 = rq[0], r1 = rq[1], r2 = rq[2], r3 = rq[3];
  const float4 c0 = cq[0], c1 = cq[1], c2 = cq[2], c3 = cq[3];
  const float bvr[16] = {r0.x + c0.x, r0.y + c0.y, r0.z + c0.z, r0.w + c0.w,
                         r1.x + c1.x, r1.y + c1.y, r1.z + c1.z, r1.w + c1.w,
                         r2.x + c2.x, r2.y + c2.y, r2.z + c2.z, r2.w + c2.w,
                         r3.x + c3.x, r3.y + c3.y, r3.z + c3.z, r3.w + c3.w};

  float best = -1e30f, second = -1e30f;
  int bi = 0, si = 0;
#pragma unroll
  for (int mm = 0; mm < 16; ++mm) {
    uint32_t o0, o1;
    threefry2x32(k0, k1, 0u, ibase + (uint32_t)mm, &o0, &o1);
    float z = bvr[mm] + gumbel_g(o0 ^ o1);
    int m = sub * 16 + mm;
    if (z > best)        { second = best; si = bi; best = z; bi = m; }
    else if (z > second) { second = z; si = m; }
  }
  // top-2 merge across the 4 sub-lanes; (v> || (v== && i<)) == first-max
#pragma unroll
  for (int dlt = 1; dlt <= 2; dlt <<= 1) {
    float ob = __shfl_xor(best, dlt);  int obi = __shfl_xor(bi, dlt);
    float os = __shfl_xor(second, dlt); int osi = __shfl_xor(si, dlt);
    bool selfWins = (best > ob) || (best == ob && bi < obi);
    if (selfWins) {
      if (ob > second || (ob == second && obi < si)) { second = ob; si = obi; }
    } else {
      if (best > os || (best == os && bi < osi)) { second = best; si = bi; }
      else { second = os; si = osi; }
      best = ob; bi = obi;
    }
  }
  // j=1 excludes j=0's winner; partner (j=0) group is g^1 = 4 lanes away
  const int w0p = __shfl_xor(bi, 4);
  const int w = ((g & 1) == 0) ? bi : ((bi == w0p) ? si : bi);
  // w is identical on all 4 lanes of the group; row r's winner lives at
  // lanes 4r..4r+3 (r = bl*4+dj local).

  // ---- gates: one-hot float4, issued early so stores drain under phase 2 ----
  {
    const int gb = lane >> 4, q = lane & 15;
    const int m0 = q * 4;
#pragma unroll
    for (int it = 0; it < 4; ++it) {
      const int gw = __shfl(w, (gb * 4 + it) * 4);   // row r = gb*4 + dj=it
      float4 v;
      v.x = (m0 + 0 == gw) ? 1.0f : 0.0f;
      v.y = (m0 + 1 == gw) ? 1.0f : 0.0f;
      v.z = (m0 + 2 == gw) ? 1.0f : 0.0f;
      v.w = (m0 + 3 == gw) ? 1.0f : 0.0f;
      gates[((size_t)it * BATCH + b0w + gb) * 16 + q] = v;
    }
  }

  // ---- phase 2: sparse MLP, one row per 16-lane group ----
  const int grp = lane >> 4, sl = lane & 15;
  const char* W1b = (const char*)W1;
  const char* B1b = (const char*)b1v;
  const char* W2b = (const char*)W2;
#pragma unroll
  for (int i = 0; i < 4; ++i) {
    const int rw = __shfl(w, (i * 4 + grp) * 4);     // row (bl=i, dj=grp)
    const int brow = b0w + i;
    const float xa = X[brow * 2 + 0], xb = X[brow * 2 + 1];
    const int off  = (rw << 10) + (sl << 5);          // W1 row: 1024 B
    const int off2 = (rw << 9)  + (sl << 5);          // b1/W2 row: 512 B
    const float4 a0a = *(const float4*)(W1b + off);
    const float4 a0b = *(const float4*)(W1b + off + 16);
    const float4 a1a = *(const float4*)(W1b + off + 512);
    const float4 a1b = *(const float4*)(W1b + off + 528);
    const float4 b1a = *(const float4*)(B1b + off2);
    const float4 b1b = *(const float4*)(B1b + off2 + 16);
    const float4 w2a = *(const float4*)(W2b + off2);
    const float4 w2b = *(const float4*)(W2b + off2 + 16);
    float h0 = fmaf(xb, a1a.x, fmaf(xa, a0a.x, b1a.x));
    float h1 = fmaf(xb, a1a.y, fmaf(xa, a0a.y, b1a.y));
    float h2 = fmaf(xb, a1a.z, fmaf(xa, a0a.z, b1a.z));
    float h3 = fmaf(xb, a1a.w, fmaf(xa, a0a.w, b1a.w));
    float h4 = fmaf(xb, a1b.x, fmaf(xa, a0b.x, b1b.x));
    float h5 = fmaf(xb, a1b.y, fmaf(xa, a0b.y, b1b.y));
    float h6 = fmaf(xb, a1b.z, fmaf(xa, a0b.z, b1b.z));
    float h7 = fmaf(xb, a1b.w, fmaf(xa, a0b.w, b1b.w));
    float s = tanh_fast(h0) * w2a.x;
    s = fmaf(tanh_fast(h1), w2a.y, s);
    s = fmaf(tanh_fast(h2), w2a.z, s);
    s = fmaf(tanh_fast(h3), w2a.w, s);
    s = fmaf(tanh_fast(h4), w2b.x, s);
    s = fmaf(tanh_fast(h5), w2b.y, s);
    s = fmaf(tanh_fast(h6), w2b.z, s);
    s = fmaf(tanh_fast(h7), w2b.w, s);
#pragma unroll
    for (int sft = 1; sft < 16; sft <<= 1) s += __shfl_xor(s, sft);
    // term for row (bl=i, dj=grp); same fp order as r4: coef * (s + b2)
    const float val = coef[grp * NM + rw] * (s + b2v[rw]);
    const float pv = __shfl_xor(val, 16);            // partner j-term
    if ((grp & 1) == 0 && sl == 0)                    // grp even = j0 lane
      out0[brow * 2 + (grp >> 1)] = val + pv;        // fl(t_j0 + t_j1)
  }
}

extern "C" void kernel_launch(void* const* d_in, const int* in_sizes, int n_in,
                              void* d_out, int out_size, void* d_ws, size_t ws_size,
                              hipStream_t stream) {
  const float* X       = (const float*)d_in[0];
  const float* W1      = (const float*)d_in[1];
  const float* b1v     = (const float*)d_in[2];
  const float* W2      = (const float*)d_in[3];
  const float* b2v     = (const float*)d_in[4];
  const float* routers = (const float*)d_in[5];
  const float* coef    = (const float*)d_in[6];
  const float* cp      = (const float*)d_in[7];
  float* out0  = (float*)d_out;
  float* gates = out0 + BATCH * 2;          // outputs concatenated flat

  // fold_in(key(42), dj) = threefry2x32((0,42), (0,dj))
  Keys keys;
  for (uint32_t dj = 0; dj < 4; ++dj) {
    uint32_t o0, o1;
    threefry2x32(0u, 42u, 0u, dj, &o0, &o1);
    keys.k[dj * 2 + 0] = o0;
    keys.k[dj * 2 + 1] = o1;
  }

  k_fused<<<dim3(BATCH / 16), dim3(256), 0, stream>>>(
      keys, X, W1, b1v, W2, b2v, routers, coef, cp, out0, (float4*)gates);
}